// Round 2
// baseline (324.295 us; speedup 1.0000x reference)
//
#include <hip/hip_runtime.h>
#include <hip/hip_cooperative_groups.h>
#include <math.h>

namespace cg = cooperative_groups;

#define BB 4
#define NN 128
#define MM 16
#define KK 80
#define CF 256
#define CSL 2048
#define CT 2304      // CF + CSL
#define TFAST 32
#define TSLOW 8
#define HH 14
#define WW 14
#define HWQ 196      // 14*14
#define NQ4 49       // HWQ/4 float4 per (b,c)

// ---- workspace layout (float offsets) ----
#define G_OFF      0
#define G_SIZE     (BB*HWQ*KK)            // 62,720     [b][cell][k]
#define FGF_OFF    (G_OFF + G_SIZE)       // 512 floats
#define ASSIGN_OFF (FGF_OFF + BB*NN)      // 512 ints (in float slots)
#define NUM_OFF    (ASSIGN_OFF + BB*NN)   // 4
#define CNT_OFF    (NUM_OFF + BB)         // 4
#define CTR_OFF    (CNT_OFF + BB)         // 1 int
#define P_OFF      (CTR_OFF + 8)          // 16B-aligned

#define NSPLIT 64                          // chunks per b == partial count
#define MAXCH  43
#define P_SIZE (NSPLIT*G_SIZE)            // 4,014,080 floats = 16 MB

#define GRID 256                           // 1 block/CU -> co-resident (coop-safe)
#define RB   245                           // reduce blocks: 245*256 == G_SIZE

__device__ __forceinline__ float logsig(float x) {
    return fminf(x, 0.f) - log1pf(expf(-fabsf(x)));
}

// =======================================================================
// Single cooperative kernel: mean+GEMM -> P | reduce+assign | loss | out
// grid 256 x 256. Phases separated by grid.sync(); LDS phases overlaid.
// =======================================================================
__global__ __launch_bounds__(256) void kall(const float* __restrict__ fastp,
                                            const float* __restrict__ slowp,
                                            const float* __restrict__ props,
                                            const float* __restrict__ gtb,
                                            const float* __restrict__ gtc,
                                            const float* __restrict__ Wc,
                                            const float* __restrict__ bcls,
                                            float* __restrict__ ws,
                                            float* __restrict__ out) {
    cg::grid_group grid = cg::this_grid();
    __shared__ union alignas(16) {
        struct { float sfeat[MAXCH*HWQ + 64]; float sW[MAXCH*KK]; } a;   // phase A
        struct { float sgt[BB*MM*4]; float sfg[BB*NN]; int sany; } b;    // phase B assign
        struct { int cells[2][49]; float red[2][128]; } c;               // phase C
    } sm;

    const int bid = blockIdx.x;
    const int tid = threadIdx.x;

    // ---------------- Phase A: fused temporal mean + split-C GEMM -> P ----
    {
        int b = bid >> 6;
        int r = bid & 63;
        int gc0, nch, T, isfast;
        if (r < 16) { isfast = 1; gc0 = r * 16; nch = 16; T = TFAST; }
        else {
            int s = r - 16;
            int c0s = (s < 32) ? (43 * s) : (1376 + 42 * (s - 32));
            nch = (s < 32) ? 43 : 42;
            gc0 = CF + c0s; T = TSLOW; isfast = 0;
        }

        const float4* base = isfast
            ? ((const float4*)fastp + (size_t)(b * CF + gc0) * TFAST * NQ4)
            : ((const float4*)slowp + (size_t)(b * CSL + (gc0 - CF)) * TSLOW * NQ4);
        const float scale = 1.f / (float)T;
        int ntasks = nch * NQ4;
        for (int x = tid; x < ntasks; x += 256) {
            int cl = x / NQ4;
            int q  = x - cl * NQ4;
            const float4* p = base + (size_t)cl * T * NQ4 + q;
            float4 a = make_float4(0.f, 0.f, 0.f, 0.f);
            #pragma unroll 8
            for (int t = 0; t < T; ++t) {
                float4 v = p[t * NQ4];
                a.x += v.x; a.y += v.y; a.z += v.z; a.w += v.w;
            }
            a.x *= scale; a.y *= scale; a.z *= scale; a.w *= scale;
            ((float4*)sm.a.sfeat)[cl * NQ4 + q] = a;
        }
        const float4* wsrc = (const float4*)Wc + (size_t)gc0 * (KK / 4);
        int wtasks = nch * (KK / 4);
        for (int x = tid; x < wtasks; x += 256) ((float4*)sm.a.sW)[x] = wsrc[x];
        __syncthreads();

        int cg_ = tid & 31;
        int kq  = tid >> 5;            // 0..7, k0 = kq*10
        float acc[7][10];
        #pragma unroll
        for (int j = 0; j < 7; ++j)
            #pragma unroll
            for (int i = 0; i < 10; ++i) acc[j][i] = 0.f;

        const float* fr = sm.a.sfeat + cg_;
        const float* wr = sm.a.sW + kq * 10;
        for (int c = 0; c < nch; ++c) {
            float w[10];
            #pragma unroll
            for (int i = 0; i < 10; ++i) w[i] = wr[c * KK + i];
            #pragma unroll
            for (int j = 0; j < 7; ++j) {
                float fv = fr[c * HWQ + 32 * j];   // j==6,cg>=4 hits pad: never stored
                #pragma unroll
                for (int i = 0; i < 10; ++i) acc[j][i] += fv * w[i];
            }
        }

        int k0 = kq * 10;
        float* P = ws + P_OFF + (size_t)r * G_SIZE + (size_t)b * (KK * HWQ);
        #pragma unroll
        for (int j = 0; j < 7; ++j) {
            int cell = cg_ + 32 * j;
            if (cell < HWQ) {
                #pragma unroll
                for (int i = 0; i < 10; ++i) P[(k0 + i) * HWQ + cell] = acc[j][i];
            }
        }
    }

    __threadfence();
    grid.sync();

    // ---------------- Phase B: reduce P -> G (blocks 0..244) | assign (255) ----
    if (bid < RB) {
        int ridx = bid * 256 + tid;            // linear over [b][k][cell], covers G_SIZE
        const float* P = ws + P_OFF;
        float s = 0.f;
        #pragma unroll 16
        for (int cs = 0; cs < NSPLIT; ++cs) s += P[(size_t)cs * G_SIZE + ridx];
        int b    = ridx / (KK * HWQ);
        int rem  = ridx - b * (KK * HWQ);
        int k    = rem / HWQ;
        int cell = rem - k * HWQ;
        ws[G_OFF + (size_t)b * HWQ * KK + cell * KK + k] = s;  // G[b][cell][k]
    } else if (bid == GRID - 1) {
        // 256 threads, 2 proposals each
        if (tid < BB*MM*4) sm.b.sgt[tid] = gtb[tid];   // 256 == BB*MM*4
        if (tid == 0) sm.b.sany = 0;
        __syncthreads();
        float bestv[2]; int argv[2]; int flag = 0;
        #pragma unroll
        for (int h = 0; h < 2; ++h) {
            int p = tid + 256 * h;
            int b = p >> 7;
            float x1 = props[p*4+0], y1 = props[p*4+1], x2 = props[p*4+2], y2 = props[p*4+3];
            float aa = (x2 - x1) * (y2 - y1);
            float best = -1.f; int arg = 0;
            for (int m = 0; m < MM; ++m) {
                const float* g = &sm.b.sgt[(b*MM + m)*4];
                float tlx = fmaxf(x1, g[0]), tly = fmaxf(y1, g[1]);
                float brx = fminf(x2, g[2]), bry = fminf(y2, g[3]);
                float inter = fmaxf(brx - tlx, 0.f) * fmaxf(bry - tly, 0.f);
                float ab = (g[2] - g[0]) * (g[3] - g[1]);
                float iou = inter / (aa + ab - inter);
                if (iou > best) { best = iou; arg = m; }   // first-max = argmax semantics
            }
            bestv[h] = best; argv[h] = arg;
            if (best >= 0.85f) flag = 1;
        }
        if (flag) atomicOr(&sm.b.sany, 1);
        __syncthreads();
        int any = sm.b.sany;
        #pragma unroll
        for (int h = 0; h < 2; ++h) {
            int p = tid + 256 * h;
            float fg = any ? (bestv[h] >= 0.85f ? 1.f : 0.f) : (bestv[h] >= 0.5f ? 1.f : 0.f);
            sm.b.sfg[p] = fg;
            ws[FGF_OFF + p] = fg;
            ((int*)ws)[ASSIGN_OFF + p] = argv[h];
        }
        __syncthreads();
        if (tid < BB) {
            float s = 0.f;
            for (int i = 0; i < NN; ++i) s += sm.b.sfg[tid*NN + i];
            ws[CNT_OFF + tid] = s;
            ws[NUM_OFF + tid] = 0.f;
        }
    }

    __threadfence();
    grid.sync();

    // ---------------- Phase C: loss, 2 proposals per block ----
    {
        int h = tid >> 7;                 // 0..1
        int t = tid & 127;
        int p = (bid << 1) | h;           // 0..511
        int b = p >> 7;
        float fgf = ws[FGF_OFF + p];
        if (t < 49) {
            int gy = t / 7, gx = t % 7;
            float x1 = props[p*4+0] * (1.f/16.f);
            float y1 = props[p*4+1] * (1.f/16.f);
            float x2 = props[p*4+2] * (1.f/16.f);
            float y2 = props[p*4+3] * (1.f/16.f);
            float gry = ((float)gy + 0.5f) / 7.f;
            float grx = ((float)gx + 0.5f) / 7.f;
            float cy = y1 + gry * (y2 - y1);
            float cx = x1 + grx * (x2 - x1);
            int iy = (int)floorf(cy); iy = min(max(iy, 0), HH-1);
            int ix = (int)floorf(cx); ix = min(max(ix, 0), WW-1);
            sm.c.cells[h][t] = iy * WW + ix;
        }
        __syncthreads();
        float lk = 0.f;
        if (t < KK) {
            float acc = 0.f;
            const float* Gb = ws + G_OFF + b * HWQ * KK + t;
            #pragma unroll 7
            for (int g = 0; g < 49; ++g) acc += Gb[sm.c.cells[h][g] * KK];
            float logit = acc * (1.f/49.f) + bcls[t];
            int a = ((const int*)ws)[ASSIGN_OFF + p];
            float y = gtc[(b*MM + a)*KK + t];
            lk = -(y * logsig(logit) + (1.f - y) * logsig(-logit));
        }
        sm.c.red[h][t] = lk;
        __syncthreads();
        for (int s = 64; s > 0; s >>= 1) {
            if (t < s) sm.c.red[h][t] += sm.c.red[h][t + s];
            __syncthreads();
        }
        if (t == 0 && fgf != 0.f)
            atomicAdd(&ws[NUM_OFF + b], sm.c.red[h][0] * (1.f/KK));
    }

    __threadfence();
    grid.sync();

    // ---------------- Phase D: finalize ----
    if (bid == 0 && tid < BB) {
        float num = ws[NUM_OFF + tid];
        float c   = ws[CNT_OFF + tid];
        out[tid] = (c > 0.f) ? num / c : 0.f;
    }
}

// =======================================================================
// Fallback chain (non-cooperative): proven-correct multi-kernel path
// =======================================================================
__global__ __launch_bounds__(256) void kz_zero(float* __restrict__ ws) {
    int idx = blockIdx.x * 256 + threadIdx.x;
    if (idx < G_SIZE) ws[G_OFF + idx] = 0.f;
}

__global__ __launch_bounds__(256) void k12_fused(const float* __restrict__ fastp,
                                                 const float* __restrict__ slowp,
                                                 const float* __restrict__ Wc,
                                                 float* __restrict__ ws) {
    __shared__ float sfeat[MAXCH*HWQ + 64];
    __shared__ float sW[MAXCH*KK];
    int bid = blockIdx.x;
    int b = bid >> 6;
    int r = bid & 63;
    int gc0, nch, T, isfast;
    if (r < 16) { isfast = 1; gc0 = r * 16; nch = 16; T = TFAST; }
    else {
        int s = r - 16;
        int c0s = (s < 32) ? (43 * s) : (1376 + 42 * (s - 32));
        nch = (s < 32) ? 43 : 42;
        gc0 = CF + c0s; T = TSLOW; isfast = 0;
    }
    int tid = threadIdx.x;

    const float4* base = isfast
        ? ((const float4*)fastp + (size_t)(b * CF + gc0) * TFAST * NQ4)
        : ((const float4*)slowp + (size_t)(b * CSL + (gc0 - CF)) * TSLOW * NQ4);
    const float scale = 1.f / (float)T;
    int ntasks = nch * NQ4;
    for (int x = tid; x < ntasks; x += 256) {
        int cl = x / NQ4;
        int q  = x - cl * NQ4;
        const float4* p = base + (size_t)cl * T * NQ4 + q;
        float4 a = make_float4(0.f, 0.f, 0.f, 0.f);
        #pragma unroll 8
        for (int t = 0; t < T; ++t) {
            float4 v = p[t * NQ4];
            a.x += v.x; a.y += v.y; a.z += v.z; a.w += v.w;
        }
        a.x *= scale; a.y *= scale; a.z *= scale; a.w *= scale;
        ((float4*)sfeat)[cl * NQ4 + q] = a;
    }
    const float4* wsrc = (const float4*)Wc + (size_t)gc0 * (KK / 4);
    int wtasks = nch * (KK / 4);
    for (int x = tid; x < wtasks; x += 256) ((float4*)sW)[x] = wsrc[x];
    __syncthreads();

    int cg_ = tid & 31;
    int kq = tid >> 5;
    float acc[7][10];
    #pragma unroll
    for (int j = 0; j < 7; ++j)
        #pragma unroll
        for (int i = 0; i < 10; ++i) acc[j][i] = 0.f;

    const float* fr = sfeat + cg_;
    const float* wr = sW + kq * 10;
    for (int c = 0; c < nch; ++c) {
        float w[10];
        #pragma unroll
        for (int i = 0; i < 10; ++i) w[i] = wr[c * KK + i];
        #pragma unroll
        for (int j = 0; j < 7; ++j) {
            float fv = fr[c * HWQ + 32 * j];
            #pragma unroll
            for (int i = 0; i < 10; ++i) acc[j][i] += fv * w[i];
        }
    }

    int k0 = kq * 10;
    float* g = ws + G_OFF + (size_t)b * HWQ * KK;
    #pragma unroll
    for (int j = 0; j < 7; ++j) {
        int cell = cg_ + 32 * j;
        if (cell < HWQ) {
            #pragma unroll
            for (int i = 0; i < 10; ++i) atomicAdd(&g[cell * KK + k0 + i], acc[j][i]);
        }
    }
}

#define RED_BLOCKS ((G_SIZE + 511) / 512)   // 123
__global__ __launch_bounds__(512) void k2b_assign(const float* __restrict__ props,
                                                  const float* __restrict__ gtb,
                                                  float* __restrict__ ws,
                                                  int use_partials) {
    int blk = blockIdx.x;
    int t = threadIdx.x;
    if (blk < RED_BLOCKS) {
        if (!use_partials) return;
        int ridx = blk * 512 + t;
        if (ridx < G_SIZE) {
            const float* P = ws + P_OFF;
            float s = 0.f;
            #pragma unroll 16
            for (int cs = 0; cs < NSPLIT; ++cs) s += P[(size_t)cs * G_SIZE + ridx];
            int b    = ridx / (KK * HWQ);
            int rem  = ridx - b * (KK * HWQ);
            int k    = rem / HWQ;
            int cell = rem - k * HWQ;
            ws[G_OFF + (size_t)b * HWQ * KK + cell * KK + k] = s;
        }
        return;
    }
    __shared__ float sgt[BB*MM*4];
    __shared__ float sfg[BB*NN];
    __shared__ int sany;
    if (t < BB*MM*4) sgt[t] = gtb[t];
    if (t == 0) sany = 0;
    __syncthreads();
    int b = t >> 7;
    float x1 = props[t*4+0], y1 = props[t*4+1], x2 = props[t*4+2], y2 = props[t*4+3];
    float aa = (x2 - x1) * (y2 - y1);
    float best = -1.f; int arg = 0;
    for (int m = 0; m < MM; ++m) {
        const float* g = &sgt[(b*MM + m)*4];
        float tlx = fmaxf(x1, g[0]), tly = fmaxf(y1, g[1]);
        float brx = fminf(x2, g[2]), bry = fminf(y2, g[3]);
        float inter = fmaxf(brx - tlx, 0.f) * fmaxf(bry - tly, 0.f);
        float ab = (g[2] - g[0]) * (g[3] - g[1]);
        float iou = inter / (aa + ab - inter);
        if (iou > best) { best = iou; arg = m; }
    }
    if (best >= 0.85f) atomicOr(&sany, 1);
    __syncthreads();
    float fg = sany ? (best >= 0.85f ? 1.f : 0.f) : (best >= 0.5f ? 1.f : 0.f);
    sfg[t] = fg;
    ws[FGF_OFF + t] = fg;
    ((int*)ws)[ASSIGN_OFF + t] = arg;
    __syncthreads();
    if (t < BB) {
        float s = 0.f;
        for (int i = 0; i < NN; ++i) s += sfg[t*NN + i];
        ws[CNT_OFF + t] = s;
        ws[NUM_OFF + t] = 0.f;
    }
    if (t == 0) ((int*)ws)[CTR_OFF] = 0;
}

__global__ __launch_bounds__(128) void k3b_loss(const float* __restrict__ props,
                                                const float* __restrict__ gtc,
                                                const float* __restrict__ bcls,
                                                float* __restrict__ ws,
                                                float* __restrict__ out) {
    int p = blockIdx.x;
    int b = p >> 7;
    int t = threadIdx.x;
    __shared__ int cells[49];
    __shared__ float red[128];
    if (ws[FGF_OFF + p] != 0.f) {
        if (t < 49) {
            int gy = t / 7, gx = t % 7;
            float x1 = props[p*4+0] * (1.f/16.f);
            float y1 = props[p*4+1] * (1.f/16.f);
            float x2 = props[p*4+2] * (1.f/16.f);
            float y2 = props[p*4+3] * (1.f/16.f);
            float gry = ((float)gy + 0.5f) / 7.f;
            float grx = ((float)gx + 0.5f) / 7.f;
            float cy = y1 + gry * (y2 - y1);
            float cx = x1 + grx * (x2 - x1);
            int iy = (int)floorf(cy); iy = min(max(iy, 0), HH-1);
            int ix = (int)floorf(cx); ix = min(max(ix, 0), WW-1);
            cells[t] = iy * WW + ix;
        }
        __syncthreads();
        float lk = 0.f;
        if (t < KK) {
            float acc = 0.f;
            const float* Gb = ws + G_OFF + b * HWQ * KK + t;
            #pragma unroll 7
            for (int g = 0; g < 49; ++g) acc += Gb[cells[g] * KK];
            float logit = acc * (1.f/49.f) + bcls[t];
            int a = ((const int*)ws)[ASSIGN_OFF + p];
            float y = gtc[(b*MM + a)*KK + t];
            lk = -(y * logsig(logit) + (1.f - y) * logsig(-logit));
        }
        red[t] = lk;
        __syncthreads();
        for (int s = 64; s > 0; s >>= 1) {
            if (t < s) red[t] += red[t + s];
            __syncthreads();
        }
        if (t == 0) atomicAdd(&ws[NUM_OFF + b], red[0] * (1.f/KK));
    }
    if (t == 0) {
        __threadfence();
        int old = atomicAdd(&((int*)ws)[CTR_OFF], 1);
        if (old == BB*NN - 1) {
            __threadfence();
            #pragma unroll
            for (int bb = 0; bb < BB; ++bb) {
                float num = atomicAdd(&ws[NUM_OFF + bb], 0.f);
                float c = ws[CNT_OFF + bb];
                out[bb] = (c > 0.f) ? num / c : 0.f;
            }
        }
    }
}

extern "C" void kernel_launch(void* const* d_in, const int* in_sizes, int n_in,
                              void* d_out, int out_size, void* d_ws, size_t ws_size,
                              hipStream_t stream) {
    const float* fastp = (const float*)d_in[0];
    const float* slowp = (const float*)d_in[1];
    const float* props = (const float*)d_in[2];
    const float* gtb   = (const float*)d_in[3];
    const float* gtc   = (const float*)d_in[4];
    const float* Wc    = (const float*)d_in[5];
    const float* bcls  = (const float*)d_in[6];
    float* ws  = (float*)d_ws;
    float* out = (float*)d_out;

    const size_t need = (size_t)(P_OFF + P_SIZE) * sizeof(float);
    if (ws_size >= need) {
        void* args[] = {(void*)&fastp, (void*)&slowp, (void*)&props, (void*)&gtb,
                        (void*)&gtc, (void*)&Wc, (void*)&bcls, (void*)&ws, (void*)&out};
        hipError_t e = hipLaunchCooperativeKernel(reinterpret_cast<void*>(kall),
                                                  dim3(GRID), dim3(256), args, 0, stream);
        if (e == hipSuccess) return;
        (void)hipGetLastError();   // clear; fall through to non-coop chain
    }

    kz_zero<<<(G_SIZE + 255)/256, 256, 0, stream>>>(ws);
    k12_fused<<<BB * NSPLIT, 256, 0, stream>>>(fastp, slowp, Wc, ws);
    k2b_assign<<<RED_BLOCKS + 1, 512, 0, stream>>>(props, gtb, ws, 0);
    k3b_loss<<<BB*NN, 128, 0, stream>>>(props, gtc, bcls, ws, out);
}

// Round 3
// 140.684 us; speedup vs baseline: 2.3051x; 2.3051x over previous
//
#include <hip/hip_runtime.h>
#include <math.h>

#define BB 4
#define NN 128
#define MM 16
#define KK 80
#define CF 256
#define CSL 2048
#define CT 2304      // CF + CSL
#define TFAST 32
#define TSLOW 8
#define HH 14
#define WW 14
#define HWQ 196      // 14*14
#define NQ4 49       // HWQ/4 float4 per (b,c)

// ---- workspace layout (float offsets) ----
#define G_OFF      0
#define G_SIZE     (BB*HWQ*KK)            // 62,720     [b][cell][k]
#define FGF_OFF    (G_OFF + G_SIZE)       // 512 floats
#define ASSIGN_OFF (FGF_OFF + BB*NN)      // 512 ints (in float slots)
#define NUM_OFF    (ASSIGN_OFF + BB*NN)   // 4
#define CNT_OFF    (NUM_OFF + BB)         // 4
#define CTR_OFF    (CNT_OFF + BB)         // 1 int
#define P_OFF      (CTR_OFF + 8)          // 16B-aligned

// 96 equal-byte chunks per b: fast 32 x (8ch,T=32), slow 64 x (32ch,T=8).
// Every chunk stages exactly 8*32*196*4 = 200KB -> balanced blocks.
#define NSPLIT 96
#define MAXCH  32
#define P_SIZE (NSPLIT*G_SIZE)            // 24.1 MB

// ---------------- K12: fused temporal-mean + split-C GEMM ----------------
// grid (96, 4) = (chunk, b), 256 thr. Block stages the temporal mean of its
// chunk into LDS (raw features read once), stages W, computes partial G for
// 196 cells x 80 k. Thread map: cg=tid&31 (cells cg+32j, j<7), kq=tid>>5
// (k=kq*10..+9). P layout [cs][b][k][cell] -> stores coalesce over cg.
__global__ __launch_bounds__(256) void k12_fused(const float* __restrict__ fastp,
                                                 const float* __restrict__ slowp,
                                                 const float* __restrict__ Wc,
                                                 float* __restrict__ ws,
                                                 int use_partials) {
    __shared__ float sfeat[MAXCH*HWQ + 64];   // +64 pad: j==6 overread guard
    __shared__ float sW[MAXCH*KK];
    const int r   = blockIdx.x;   // 0..95
    const int b   = blockIdx.y;   // 0..3
    const int tid = threadIdx.x;
    int gc0, nch;
    if (r < 32) { gc0 = r * 8;              nch = 8;  }
    else        { gc0 = CF + (r - 32) * 32; nch = 32; }

    // ---- stage temporal mean of this chunk into sfeat[cl][hw] ----
    if (r < 32) {           // fast path, T=32 compile-time
        const float4* base = (const float4*)fastp + (size_t)(b * CF + gc0) * TFAST * NQ4;
        const int ntasks = 8 * NQ4;          // 392
        for (int x = tid; x < ntasks; x += 256) {
            int cl = x / NQ4;
            int q  = x - cl * NQ4;
            const float4* p = base + (size_t)cl * TFAST * NQ4 + q;
            float4 a = make_float4(0.f, 0.f, 0.f, 0.f);
            #pragma unroll 8
            for (int t = 0; t < TFAST; ++t) {
                float4 v = p[t * NQ4];
                a.x += v.x; a.y += v.y; a.z += v.z; a.w += v.w;
            }
            const float s = 1.f / (float)TFAST;
            a.x *= s; a.y *= s; a.z *= s; a.w *= s;
            ((float4*)sfeat)[cl * NQ4 + q] = a;
        }
    } else {                // slow path, T=8 compile-time
        const float4* base = (const float4*)slowp + (size_t)(b * CSL + (gc0 - CF)) * TSLOW * NQ4;
        const int ntasks = 32 * NQ4;         // 1568
        for (int x = tid; x < ntasks; x += 256) {
            int cl = x / NQ4;
            int q  = x - cl * NQ4;
            const float4* p = base + (size_t)cl * TSLOW * NQ4 + q;
            float4 a = make_float4(0.f, 0.f, 0.f, 0.f);
            #pragma unroll
            for (int t = 0; t < TSLOW; ++t) {
                float4 v = p[t * NQ4];
                a.x += v.x; a.y += v.y; a.z += v.z; a.w += v.w;
            }
            const float s = 1.f / (float)TSLOW;
            a.x *= s; a.y *= s; a.z *= s; a.w *= s;
            ((float4*)sfeat)[cl * NQ4 + q] = a;
        }
    }
    // ---- stage W rows [gc0, gc0+nch) ----
    const float4* wsrc = (const float4*)Wc + (size_t)gc0 * (KK / 4);
    int wtasks = nch * (KK / 4);
    for (int x = tid; x < wtasks; x += 256) ((float4*)sW)[x] = wsrc[x];
    __syncthreads();

    // ---- GEMM: partial G over this chunk's channels ----
    int cg = tid & 31;
    int kq = tid >> 5;            // 0..7, k0 = kq*10
    float acc[7][10];
    #pragma unroll
    for (int j = 0; j < 7; ++j)
        #pragma unroll
        for (int i = 0; i < 10; ++i) acc[j][i] = 0.f;

    const float* fr = sfeat + cg;
    const float* wr = sW + kq * 10;
    for (int c = 0; c < nch; ++c) {
        float w[10];
        #pragma unroll
        for (int i = 0; i < 10; ++i) w[i] = wr[c * KK + i];
        #pragma unroll
        for (int j = 0; j < 7; ++j) {
            float fv = fr[c * HWQ + 32 * j];   // j==6,cg>=4 hits pad: never stored
            #pragma unroll
            for (int i = 0; i < 10; ++i) acc[j][i] += fv * w[i];
        }
    }

    int k0 = kq * 10;
    if (use_partials) {
        // P[r][b][k][cell] — coalesced over cg
        float* P = ws + P_OFF + (size_t)r * G_SIZE + (size_t)b * (KK * HWQ);
        #pragma unroll
        for (int j = 0; j < 7; ++j) {
            int cell = cg + 32 * j;
            if (cell < HWQ) {
                #pragma unroll
                for (int i = 0; i < 10; ++i) P[(k0 + i) * HWQ + cell] = acc[j][i];
            }
        }
    } else {
        float* g = ws + G_OFF + (size_t)b * HWQ * KK;
        #pragma unroll
        for (int j = 0; j < 7; ++j) {
            int cell = cg + 32 * j;
            if (cell < HWQ) {
                #pragma unroll
                for (int i = 0; i < 10; ++i) atomicAdd(&g[cell * KK + k0 + i], acc[j][i]);
            }
        }
    }
}

// ---------------- fallback: zero G (only when ws too small for P) ----------------
__global__ __launch_bounds__(256) void kz_zero(float* __restrict__ ws) {
    int idx = blockIdx.x * 256 + threadIdx.x;
    if (idx < G_SIZE) ws[G_OFF + idx] = 0.f;
}

// ---------------- K2b: reduce partials (blocks 0..244) + IoU assign (block 245) ----
// 245*256 == G_SIZE exactly: every CU busy during the reduce.
#define RED_BLOCKS (G_SIZE / 256)           // 245
__global__ __launch_bounds__(256) void k2b_assign(const float* __restrict__ props,
                                                  const float* __restrict__ gtb,
                                                  float* __restrict__ ws,
                                                  int use_partials) {
    int blk = blockIdx.x;
    int t = threadIdx.x;
    if (blk < RED_BLOCKS) {
        if (!use_partials) return;
        int ridx = blk * 256 + t;            // linear over [b][k][cell]
        const float* P = ws + P_OFF;
        float s = 0.f;
        #pragma unroll 16
        for (int cs = 0; cs < NSPLIT; ++cs) s += P[(size_t)cs * G_SIZE + ridx];
        int b    = ridx / (KK * HWQ);
        int rem  = ridx - b * (KK * HWQ);
        int k    = rem / HWQ;
        int cell = rem - k * HWQ;
        ws[G_OFF + (size_t)b * HWQ * KK + cell * KK + k] = s;  // G[b][cell][k]
        return;
    }
    // ---- assignment block: 256 threads, 2 proposals each ----
    __shared__ float sgt[BB*MM*4];
    __shared__ float sfg[BB*NN];
    __shared__ int sany;
    if (t < BB*MM*4) sgt[t] = gtb[t];        // 256 == BB*MM*4
    if (t == 0) sany = 0;
    __syncthreads();
    float bestv[2]; int argv[2]; int flag = 0;
    #pragma unroll
    for (int h = 0; h < 2; ++h) {
        int p = t + 256 * h;
        int b = p >> 7;
        float x1 = props[p*4+0], y1 = props[p*4+1], x2 = props[p*4+2], y2 = props[p*4+3];
        float aa = (x2 - x1) * (y2 - y1);
        float best = -1.f; int arg = 0;
        for (int m = 0; m < MM; ++m) {
            const float* g = &sgt[(b*MM + m)*4];
            float tlx = fmaxf(x1, g[0]), tly = fmaxf(y1, g[1]);
            float brx = fminf(x2, g[2]), bry = fminf(y2, g[3]);
            float inter = fmaxf(brx - tlx, 0.f) * fmaxf(bry - tly, 0.f);
            float ab = (g[2] - g[0]) * (g[3] - g[1]);
            float iou = inter / (aa + ab - inter);
            if (iou > best) { best = iou; arg = m; }   // first-max = argmax semantics
        }
        bestv[h] = best; argv[h] = arg;
        if (best >= 0.85f) flag = 1;
    }
    if (flag) atomicOr(&sany, 1);
    __syncthreads();
    int any = sany;
    #pragma unroll
    for (int h = 0; h < 2; ++h) {
        int p = t + 256 * h;
        float fg = any ? (bestv[h] >= 0.85f ? 1.f : 0.f) : (bestv[h] >= 0.5f ? 1.f : 0.f);
        sfg[p] = fg;
        ws[FGF_OFF + p] = fg;
        ((int*)ws)[ASSIGN_OFF + p] = argv[h];
    }
    __syncthreads();
    if (t < BB) {
        float s = 0.f;
        for (int i = 0; i < NN; ++i) s += sfg[t*NN + i];
        ws[CNT_OFF + t] = s;
        ws[NUM_OFF + t] = 0.f;
    }
    if (t == 0) ((int*)ws)[CTR_OFF] = 0;
}

// ---------------- K3b: per-proposal loss + last-block finalize ----------------
__device__ __forceinline__ float logsig(float x) {
    return fminf(x, 0.f) - log1pf(expf(-fabsf(x)));
}

__global__ __launch_bounds__(128) void k3b_loss(const float* __restrict__ props,
                                                const float* __restrict__ gtc,
                                                const float* __restrict__ bcls,
                                                float* __restrict__ ws,
                                                float* __restrict__ out) {
    int p = blockIdx.x;
    int b = p >> 7;
    int t = threadIdx.x;
    __shared__ int cells[49];
    __shared__ float red[128];
    if (ws[FGF_OFF + p] != 0.f) {
        if (t < 49) {
            int gy = t / 7, gx = t % 7;
            float x1 = props[p*4+0] * (1.f/16.f);
            float y1 = props[p*4+1] * (1.f/16.f);
            float x2 = props[p*4+2] * (1.f/16.f);
            float y2 = props[p*4+3] * (1.f/16.f);
            float gry = ((float)gy + 0.5f) / 7.f;
            float grx = ((float)gx + 0.5f) / 7.f;
            float cy = y1 + gry * (y2 - y1);
            float cx = x1 + grx * (x2 - x1);
            int iy = (int)floorf(cy); iy = min(max(iy, 0), HH-1);
            int ix = (int)floorf(cx); ix = min(max(ix, 0), WW-1);
            cells[t] = iy * WW + ix;
        }
        __syncthreads();
        float lk = 0.f;
        if (t < KK) {
            float acc = 0.f;
            const float* Gb = ws + G_OFF + b * HWQ * KK + t;
            #pragma unroll 7
            for (int g = 0; g < 49; ++g) acc += Gb[cells[g] * KK];
            float logit = acc * (1.f/49.f) + bcls[t];
            int a = ((const int*)ws)[ASSIGN_OFF + p];
            float y = gtc[(b*MM + a)*KK + t];
            lk = -(y * logsig(logit) + (1.f - y) * logsig(-logit));
        }
        red[t] = lk;
        __syncthreads();
        for (int s = 64; s > 0; s >>= 1) {
            if (t < s) red[t] += red[t + s];
            __syncthreads();
        }
        if (t == 0) atomicAdd(&ws[NUM_OFF + b], red[0] * (1.f/KK));
    }
    if (t == 0) {
        __threadfence();
        int old = atomicAdd(&((int*)ws)[CTR_OFF], 1);
        if (old == BB*NN - 1) {
            __threadfence();
            #pragma unroll
            for (int bb = 0; bb < BB; ++bb) {
                float num = atomicAdd(&ws[NUM_OFF + bb], 0.f);
                float c = ws[CNT_OFF + bb];
                out[bb] = (c > 0.f) ? num / c : 0.f;
            }
        }
    }
}

extern "C" void kernel_launch(void* const* d_in, const int* in_sizes, int n_in,
                              void* d_out, int out_size, void* d_ws, size_t ws_size,
                              hipStream_t stream) {
    const float* fastp = (const float*)d_in[0];
    const float* slowp = (const float*)d_in[1];
    const float* props = (const float*)d_in[2];
    const float* gtb   = (const float*)d_in[3];
    const float* gtc   = (const float*)d_in[4];
    const float* Wc    = (const float*)d_in[5];
    const float* bcls  = (const float*)d_in[6];
    float* ws  = (float*)d_ws;
    float* out = (float*)d_out;

    const size_t need = (size_t)(P_OFF + P_SIZE) * sizeof(float);
    const int use_partials = (ws_size >= need) ? 1 : 0;   // deterministic -> graph-safe

    if (!use_partials)
        kz_zero<<<(G_SIZE + 255)/256, 256, 0, stream>>>(ws);
    k12_fused<<<dim3(NSPLIT, BB), 256, 0, stream>>>(fastp, slowp, Wc, ws, use_partials);
    k2b_assign<<<RED_BLOCKS + 1, 256, 0, stream>>>(props, gtb, ws, use_partials);
    k3b_loss<<<BB*NN, 128, 0, stream>>>(props, gtc, bcls, ws, out);
}